// Round 1
// baseline (72.102 us; speedup 1.0000x reference)
//
#include <hip/hip_runtime.h>
#include <math.h>

#define NPIX 512
#define NK 11            // low-frequency k = 0..10 (i+j <= 10 triangle fits in 11x11 corner)
#define NPAIR 121        // 11*11 (invalid k+l>10 zeroed in finalize)
#define RBLKS 8          // row-blocks per channel (64 rows each)
#define NCH 96           // 32*3 channels

#define PI_D 3.14159265358979323846

// ---------------------------------------------------------------------------
// K0: cosine table C[k][h] = 2*cos(pi*(2h+1)*k / (2*512)), k<11, h<512.
// Double-precision cos to match numpy's table construction.
// ---------------------------------------------------------------------------
__global__ void build_C(float* __restrict__ Ct) {
    int k = blockIdx.x;
    int h = threadIdx.x;
    double v = 2.0 * cos(PI_D * (double)((2 * h + 1) * k) / 1024.0);
    Ct[k * NPIX + h] = (float)v;
}

// ---------------------------------------------------------------------------
// K1: per (channel, row-block) partial low-frequency coefficients.
//   A[k][w] = sum_{h in block} C[k][h] * im[h][w]      (held reg -> LDS)
//   plow[k][l] = sum_w A[k][w] * C[l][w]
// 256 threads: 128 float4-column groups x 2 row-halves (32 rows each).
// ---------------------------------------------------------------------------
#define AS_LD 516  // pad 512 -> 516 floats: keeps 16B alignment, spreads banks
__global__ __launch_bounds__(256) void k_partial(const float* __restrict__ im,
                                                 const float* __restrict__ Ct,
                                                 float* __restrict__ plow) {
    __shared__ float Cs[NK][NPIX];
    __shared__ float As[NK][AS_LD];

    int bid = blockIdx.x;
    int c = bid >> 3, rb = bid & 7;
    int t = threadIdx.x;

    for (int i = t; i < NK * NPIX; i += 256) ((float*)Cs)[i] = Ct[i];
    __syncthreads();

    int half = t >> 7;
    int col4 = t & 127;
    int w0 = col4 * 4;
    int rowbase = rb * 64 + half * 32;
    const float* imc = im + (size_t)c * NPIX * NPIX;

    float a[NK][4];
#pragma unroll
    for (int k = 0; k < NK; ++k)
        for (int j = 0; j < 4; ++j) a[k][j] = 0.f;

    for (int i = 0; i < 32; ++i) {
        int h = rowbase + i;
        float4 v = *(const float4*)(imc + (size_t)h * NPIX + w0);
#pragma unroll
        for (int k = 0; k < NK; ++k) {
            float ch = Cs[k][h];  // broadcast read
            a[k][0] += ch * v.x;
            a[k][1] += ch * v.y;
            a[k][2] += ch * v.z;
            a[k][3] += ch * v.w;
        }
    }

    // combine the two row-halves into As
    if (half == 0) {
#pragma unroll
        for (int k = 0; k < NK; ++k)
            *(float4*)&As[k][w0] = make_float4(a[k][0], a[k][1], a[k][2], a[k][3]);
    }
    __syncthreads();
    if (half == 1) {
#pragma unroll
        for (int k = 0; k < NK; ++k) {
            float4 cur = *(float4*)&As[k][w0];
            cur.x += a[k][0]; cur.y += a[k][1]; cur.z += a[k][2]; cur.w += a[k][3];
            *(float4*)&As[k][w0] = cur;
        }
    }
    __syncthreads();

    // contraction over w: 16 lanes per k, each lane strides w by 16
    int k = t >> 4;
    int sub = t & 15;
    if (k < NK) {
        float* outp = plow + (size_t)bid * NPAIR + k * NK;
        for (int l = 0; l < NK; ++l) {
            float acc = 0.f;
#pragma unroll
            for (int wi = 0; wi < 32; ++wi) {
                int w = wi * 16 + sub;
                acc += As[k][w] * Cs[l][w];
            }
            acc += __shfl_xor(acc, 8);
            acc += __shfl_xor(acc, 4);
            acc += __shfl_xor(acc, 2);
            acc += __shfl_xor(acc, 1);
            if (sub == 0) outp[l] = acc;
        }
    }
}

// ---------------------------------------------------------------------------
// K2: sum the 8 row-block partials, apply idct scales, zero k+l>10.
//   lows[c][k*11+l] = s_k * s_l * sum_b plow[c][b][k*11+l]   (s_k = w_k/1024)
// ---------------------------------------------------------------------------
__global__ void k_final(const float* __restrict__ plow, float* __restrict__ lows) {
    int c = blockIdx.x;
    int t = threadIdx.x;
    if (t >= NPAIR) return;
    int k = t / NK, l = t % NK;
    float s = 0.f;
    for (int b = 0; b < RBLKS; ++b) s += plow[((size_t)c * RBLKS + b) * NPAIR + t];
    float sk = (k == 0 ? 0.5f : 1.0f) * (1.0f / 1024.0f);
    float sl = (l == 0 ? 0.5f : 1.0f) * (1.0f / 1024.0f);
    lows[(size_t)c * NPAIR + t] = (k + l <= 10) ? s * sk * sl : 0.f;
}

// ---------------------------------------------------------------------------
// K3: out = im - rank-66 correction.
//   B[k][w] = sum_l lows[k][l] * C[l][w]   (per-thread registers, 4 cols)
//   corr[h][w] = sum_k C[k][h] * B[k][w]
// ---------------------------------------------------------------------------
__global__ __launch_bounds__(256) void k_output(const float* __restrict__ im,
                                                const float* __restrict__ Ct,
                                                const float* __restrict__ lows,
                                                float* __restrict__ out) {
    __shared__ float Cs[NK][NPIX];
    __shared__ float Ls[NPAIR];

    int bid = blockIdx.x;
    int c = bid >> 3, rb = bid & 7;
    int t = threadIdx.x;

    for (int i = t; i < NK * NPIX; i += 256) ((float*)Cs)[i] = Ct[i];
    if (t < NPAIR) Ls[t] = lows[(size_t)c * NPAIR + t];
    __syncthreads();

    int half = t >> 7;
    int col4 = t & 127;
    int w0 = col4 * 4;
    int rowbase = rb * 64 + half * 32;

    // build per-thread B[k][0..3] for this thread's 4 columns
    float B[NK][4];
#pragma unroll
    for (int k = 0; k < NK; ++k)
        for (int j = 0; j < 4; ++j) B[k][j] = 0.f;

#pragma unroll
    for (int l = 0; l < NK; ++l) {
        float4 cl = *(const float4*)&Cs[l][w0];
#pragma unroll
        for (int k = 0; k < NK; ++k) {
            float lw = Ls[k * NK + l];  // broadcast read
            B[k][0] += lw * cl.x;
            B[k][1] += lw * cl.y;
            B[k][2] += lw * cl.z;
            B[k][3] += lw * cl.w;
        }
    }

    const float* imc = im + (size_t)c * NPIX * NPIX;
    float* outc = out + (size_t)c * NPIX * NPIX;

    for (int i = 0; i < 32; ++i) {
        int h = rowbase + i;
        float4 v = *(const float4*)(imc + (size_t)h * NPIX + w0);
        float c0 = 0.f, c1 = 0.f, c2 = 0.f, c3 = 0.f;
#pragma unroll
        for (int k = 0; k < NK; ++k) {
            float ch = Cs[k][h];  // broadcast read
            c0 += ch * B[k][0];
            c1 += ch * B[k][1];
            c2 += ch * B[k][2];
            c3 += ch * B[k][3];
        }
        float4 o = make_float4(v.x - c0, v.y - c1, v.z - c2, v.w - c3);
        *(float4*)(outc + (size_t)h * NPIX + w0) = o;
    }
}

// ---------------------------------------------------------------------------
// Launch: im (32,3,512,512) f32 -> out same shape.
// ws layout (floats): [Ct: 11*512][plow: 96*8*121][lows: 96*121] ~ 431 KB
// ---------------------------------------------------------------------------
extern "C" void kernel_launch(void* const* d_in, const int* in_sizes, int n_in,
                              void* d_out, int out_size, void* d_ws, size_t ws_size,
                              hipStream_t stream) {
    const float* im = (const float*)d_in[0];
    float* out = (float*)d_out;

    float* ws = (float*)d_ws;
    float* Ct = ws;                              // 5632 floats
    float* plow = Ct + NK * NPIX;                // 92928 floats
    float* lows = plow + (size_t)NCH * RBLKS * NPAIR;  // 11616 floats

    build_C<<<NK, NPIX, 0, stream>>>(Ct);
    k_partial<<<NCH * RBLKS, 256, 0, stream>>>(im, Ct, plow);
    k_final<<<NCH, 128, 0, stream>>>(plow, lows);
    k_output<<<NCH * RBLKS, 256, 0, stream>>>(im, Ct, lows, out);
}

// Round 2
// 67.354 us; speedup vs baseline: 1.0705x; 1.0705x over previous
//
#include <hip/hip_runtime.h>
#include <math.h>

#define NPIX 512
#define NK 11            // low-frequency k = 0..10 (i+j <= 10 triangle fits in 11x11 corner)
#define NPAIR 121        // 11*11 (invalid k+l>10 zeroed in the reduce)
#define RBLKS 8          // row-blocks per channel (64 rows each)
#define NCH 96           // 32*3 channels

#define PI_F 3.14159265358979323846f

// Build the 11x512 cosine table into LDS: C[k][h] = 2*cos(pi*(2h+1)*k/1024).
// Exact integer mod-2048 range reduction keeps the fp32 cosf argument in
// [0, 2pi), matching the numpy double-built table to ~5e-7.
__device__ inline void build_Cs(float (*Cs)[NPIX], int t) {
#pragma unroll
    for (int i = t; i < NK * NPIX; i += 256) {
        int k = i >> 9;
        int h = i & 511;
        int m = ((2 * h + 1) * k) & 2047;
        float ang = (float)m * (PI_F / 1024.0f);
        ((float*)Cs)[i] = 2.0f * cosf(ang);
    }
}

// ---------------------------------------------------------------------------
// K1: per (channel, row-block) partial low-frequency coefficients.
//   A[k][w] = sum_{h in block} C[k][h] * im[h][w]      (regs -> LDS)
//   plow[k][l] = sum_w A[k][w] * C[l][w]
// 256 threads: 128 float4-column groups x 2 row-halves (32 rows each).
// ---------------------------------------------------------------------------
#define AS_LD 516  // pad 512 -> 516 floats: keeps 16B alignment, spreads banks
__global__ __launch_bounds__(256) void k_partial(const float* __restrict__ im,
                                                 float* __restrict__ plow) {
    __shared__ float Cs[NK][NPIX];
    __shared__ float As[NK][AS_LD];

    int bid = blockIdx.x;
    int c = bid >> 3, rb = bid & 7;
    int t = threadIdx.x;

    build_Cs(Cs, t);
    __syncthreads();

    int half = t >> 7;
    int col4 = t & 127;
    int w0 = col4 * 4;
    int rowbase = rb * 64 + half * 32;
    const float* imc = im + (size_t)c * NPIX * NPIX;

    float a[NK][4];
#pragma unroll
    for (int k = 0; k < NK; ++k)
        for (int j = 0; j < 4; ++j) a[k][j] = 0.f;

    for (int i = 0; i < 32; ++i) {
        int h = rowbase + i;
        float4 v = *(const float4*)(imc + (size_t)h * NPIX + w0);
#pragma unroll
        for (int k = 0; k < NK; ++k) {
            float ch = Cs[k][h];  // broadcast read
            a[k][0] += ch * v.x;
            a[k][1] += ch * v.y;
            a[k][2] += ch * v.z;
            a[k][3] += ch * v.w;
        }
    }

    // combine the two row-halves into As
    if (half == 0) {
#pragma unroll
        for (int k = 0; k < NK; ++k)
            *(float4*)&As[k][w0] = make_float4(a[k][0], a[k][1], a[k][2], a[k][3]);
    }
    __syncthreads();
    if (half == 1) {
#pragma unroll
        for (int k = 0; k < NK; ++k) {
            float4 cur = *(float4*)&As[k][w0];
            cur.x += a[k][0]; cur.y += a[k][1]; cur.z += a[k][2]; cur.w += a[k][3];
            *(float4*)&As[k][w0] = cur;
        }
    }
    __syncthreads();

    // contraction over w: 16 lanes per k, each lane strides w by 16
    int k = t >> 4;
    int sub = t & 15;
    if (k < NK) {
        float* outp = plow + (size_t)bid * NPAIR + k * NK;
        for (int l = 0; l < NK; ++l) {
            float acc = 0.f;
#pragma unroll
            for (int wi = 0; wi < 32; ++wi) {
                int w = wi * 16 + sub;
                acc += As[k][w] * Cs[l][w];
            }
            acc += __shfl_xor(acc, 8);
            acc += __shfl_xor(acc, 4);
            acc += __shfl_xor(acc, 2);
            acc += __shfl_xor(acc, 1);
            if (sub == 0) outp[l] = acc;
        }
    }
}

// ---------------------------------------------------------------------------
// K2: out = im - rank-66 correction (finalize fused in).
//   Ls[k][l] = s_k*s_l * sum_b plow[c][b][k][l], zeroed for k+l>10
//   B[k][w]  = sum_l Ls[k][l] * C[l][w]   (per-thread registers, 4 cols)
//   corr[h][w] = sum_k C[k][h] * B[k][w]
// ---------------------------------------------------------------------------
__global__ __launch_bounds__(256) void k_output(const float* __restrict__ im,
                                                const float* __restrict__ plow,
                                                float* __restrict__ out) {
    __shared__ float Cs[NK][NPIX];
    __shared__ float Ls[NPAIR];

    int bid = blockIdx.x;
    int c = bid >> 3, rb = bid & 7;
    int t = threadIdx.x;

    build_Cs(Cs, t);

    if (t < NPAIR) {
        int k = t / NK, l = t % NK;
        float s = 0.f;
        const float* pp = plow + (size_t)c * RBLKS * NPAIR + t;
#pragma unroll
        for (int b = 0; b < RBLKS; ++b) s += pp[b * NPAIR];
        float sk = (k == 0 ? 0.5f : 1.0f) * (1.0f / 1024.0f);
        float sl = (l == 0 ? 0.5f : 1.0f) * (1.0f / 1024.0f);
        Ls[t] = (k + l <= 10) ? s * sk * sl : 0.f;
    }
    __syncthreads();

    int half = t >> 7;
    int col4 = t & 127;
    int w0 = col4 * 4;
    int rowbase = rb * 64 + half * 32;

    // build per-thread B[k][0..3] for this thread's 4 columns
    float B[NK][4];
#pragma unroll
    for (int k = 0; k < NK; ++k)
        for (int j = 0; j < 4; ++j) B[k][j] = 0.f;

#pragma unroll
    for (int l = 0; l < NK; ++l) {
        float4 cl = *(const float4*)&Cs[l][w0];
#pragma unroll
        for (int k = 0; k < NK; ++k) {
            float lw = Ls[k * NK + l];  // broadcast read
            B[k][0] += lw * cl.x;
            B[k][1] += lw * cl.y;
            B[k][2] += lw * cl.z;
            B[k][3] += lw * cl.w;
        }
    }

    const float* imc = im + (size_t)c * NPIX * NPIX;
    float* outc = out + (size_t)c * NPIX * NPIX;

    for (int i = 0; i < 32; ++i) {
        int h = rowbase + i;
        float4 v = *(const float4*)(imc + (size_t)h * NPIX + w0);
        float c0 = 0.f, c1 = 0.f, c2 = 0.f, c3 = 0.f;
#pragma unroll
        for (int k = 0; k < NK; ++k) {
            float ch = Cs[k][h];  // broadcast read
            c0 += ch * B[k][0];
            c1 += ch * B[k][1];
            c2 += ch * B[k][2];
            c3 += ch * B[k][3];
        }
        float4 o = make_float4(v.x - c0, v.y - c1, v.z - c2, v.w - c3);
        *(float4*)(outc + (size_t)h * NPIX + w0) = o;
    }
}

// ---------------------------------------------------------------------------
// Launch: im (32,3,512,512) f32 -> out same shape.
// ws layout (floats): [plow: 96*8*121] ~ 372 KB
// ---------------------------------------------------------------------------
extern "C" void kernel_launch(void* const* d_in, const int* in_sizes, int n_in,
                              void* d_out, int out_size, void* d_ws, size_t ws_size,
                              hipStream_t stream) {
    const float* im = (const float*)d_in[0];
    float* out = (float*)d_out;
    float* plow = (float*)d_ws;  // NCH*RBLKS*NPAIR floats

    k_partial<<<NCH * RBLKS, 256, 0, stream>>>(im, plow);
    k_output<<<NCH * RBLKS, 256, 0, stream>>>(im, plow, out);
}